// Round 1
// baseline (1430.979 us; speedup 1.0000x reference)
//
#include <hip/hip_runtime.h>
#include <cstdint>

using u32 = unsigned int;
using u64 = unsigned long long;

#define WDIM 512
#define HDIM 512
#define CHANNELS 80   // 8 batches * 10 classes
#define NBINS 8192
#define CAP 4096
#define TOPK 100
#define NEG_SENTINEL -1e30f

// ---- workspace layout (bytes) ----
// hist:   [CHANNELS][NBINS] u32          @ 0          (2,621,440)
// cnt:    [CHANNELS] i32                 @ 2621440    (320)
// thresh: [CHANNELS] i32                 @ 2621760    (320)
// cv:     [CHANNELS][CAP] f32            @ 2622080    (1,310,720)
// ci:     [CHANNELS][CAP] i32            @ 3932800    (1,310,720)
// s1s:    [CHANNELS][TOPK] f32           @ 5243520    (32,000)
// s1i:    [CHANNELS][TOPK] i32           @ 5275520    (32,000)
#define OFF_HIST   0
#define OFF_CNT    2621440
#define OFF_THRESH 2621760
#define OFF_CV     2622080
#define OFF_CI     3932800
#define OFF_S1S    5243520
#define OFF_S1I    5275520
#define ZERO_BYTES 2621760   // hist + cnt must be zeroed every call

__device__ __forceinline__ float fmax3(float a, float b, float c) {
  return fmaxf(fmaxf(a, b), c);
}

__device__ __forceinline__ void load_row(const float* __restrict__ chbase, int y,
                                         int x0, float* r) {
  if (y < 0 || y >= HDIM) {
#pragma unroll
    for (int i = 0; i < 10; i++) r[i] = NEG_SENTINEL;
    return;
  }
  const float* row = chbase + (size_t)y * WDIM;
  float4 a = *reinterpret_cast<const float4*>(row + x0);
  float4 b = *reinterpret_cast<const float4*>(row + x0 + 4);
  r[0] = (x0 > 0) ? row[x0 - 1] : NEG_SENTINEL;
  r[1] = a.x; r[2] = a.y; r[3] = a.z; r[4] = a.w;
  r[5] = b.x; r[6] = b.y; r[7] = b.z; r[8] = b.w;
  r[9] = (x0 + 8 < WDIM) ? row[x0 + 8] : NEG_SENTINEL;
}

// One pass over heat: compute 3x3 NMS survivors.
// COLLECT=false: build per-channel histogram of survivor values (LDS hist).
// COLLECT=true : gather (value,index) of survivors with bin >= thresh[ch].
template <bool COLLECT>
__global__ __launch_bounds__(256) void nms_kernel(
    const float* __restrict__ heat, u32* __restrict__ hist,
    const int* __restrict__ thresh, float* __restrict__ cv,
    int* __restrict__ ci, int* __restrict__ cnt) {
  const int ch = blockIdx.y;
  const float* chbase = heat + (size_t)ch * (WDIM * HDIM);

  __shared__ u32 lhist[COLLECT ? 1 : NBINS];
  if constexpr (!COLLECT) {
    for (int i = threadIdx.x; i < NBINS; i += 256) lhist[i] = 0;
    __syncthreads();
  }
  int T = 0;
  if constexpr (COLLECT) T = thresh[ch];

  const int P = blockIdx.x * 2048 + threadIdx.x * 8;  // 8 px per thread, one row
  const int y = P >> 9;
  const int x0 = P & 511;

  float rm1[10], r0[10], rp1[10];
  load_row(chbase, y - 1, x0, rm1);
  load_row(chbase, y,     x0, r0);
  load_row(chbase, y + 1, x0, rp1);

#pragma unroll
  for (int i = 0; i < 8; i++) {
    float v = r0[i + 1];
    float m = fmax3(fmax3(rm1[i], rm1[i + 1], rm1[i + 2]),
                    fmax3(r0[i],  v,          r0[i + 2]),
                    fmax3(rp1[i], rp1[i + 1], rp1[i + 2]));
    if (v == m && v > 0.0f) {  // local max with positive score
      int bin = (int)(__float_as_uint(v) >> 17);
      if constexpr (!COLLECT) {
        atomicAdd(&lhist[bin], 1u);
      } else {
        if (bin >= T) {
          int pos = atomicAdd(&cnt[ch], 1);
          if (pos < CAP) {
            cv[ch * CAP + pos] = v;
            ci[ch * CAP + pos] = P + i;
          }
        }
      }
    }
  }

  if constexpr (!COLLECT) {
    __syncthreads();
    for (int i = threadIdx.x; i < NBINS; i += 256) {
      u32 c = lhist[i];
      if (c) atomicAdd(&hist[ch * NBINS + i], c);
    }
  }
}

// Per-channel: find smallest bin T with suffix_count(T) >= TOPK.
__global__ __launch_bounds__(256) void thresh_kernel(const u32* __restrict__ hist,
                                                     int* __restrict__ thresh) {
  const int ch = blockIdx.x;
  const u32* h = hist + (size_t)ch * NBINS;
  __shared__ u32 csum[256];
  const int t = threadIdx.x;
  u32 s = 0;
#pragma unroll 4
  for (int i = 0; i < NBINS / 256; i++) s += h[t * (NBINS / 256) + i];
  csum[t] = s;
  __syncthreads();
  if (t == 0) {
    u32 cum = 0;
    int c;
    for (c = 255; c >= 0; c--) {
      if (cum + csum[c] >= TOPK) break;
      cum += csum[c];
    }
    int T = 0;
    if (c >= 0) {
      int b;
      for (b = c * (NBINS / 256) + (NBINS / 256) - 1; b >= c * (NBINS / 256); b--) {
        cum += h[b];
        if (cum >= TOPK) break;
      }
      T = b;
    }
    thresh[ch] = T;
  }
}

// key = (float_bits(v) << 32) | ~index : descending sort gives
// (value desc, index asc on ties) == lax.top_k order.
__device__ __forceinline__ void bitonic_desc(u64* keys, int N, int nthr, int tid) {
  for (unsigned size = 2; size <= (unsigned)N; size <<= 1) {
    for (unsigned stride = size >> 1; stride > 0; stride >>= 1) {
      __syncthreads();
      for (unsigned i = tid; i < (unsigned)N; i += nthr) {
        unsigned j = i ^ stride;
        if (j > i) {
          u64 a = keys[i], b = keys[j];
          bool desc = ((i & size) == 0);
          if ((a < b) == desc) { keys[i] = b; keys[j] = a; }
        }
      }
    }
  }
  __syncthreads();
}

// Per-channel exact top-100 of the collected candidates.
__global__ __launch_bounds__(1024) void select_kernel(
    const float* __restrict__ cv, const int* __restrict__ ci,
    const int* __restrict__ cnt, float* __restrict__ s1s, int* __restrict__ s1i) {
  const int ch = blockIdx.x;
  __shared__ u64 keys[CAP];
  const int n = min(cnt[ch], CAP);
  for (int i = threadIdx.x; i < CAP; i += 1024) {
    u64 k = 0;
    if (i < n) {
      u32 vb = __float_as_uint(cv[ch * CAP + i]);
      u32 ib = ~(u32)ci[ch * CAP + i];
      k = ((u64)vb << 32) | ib;
    }
    keys[i] = k;
  }
  bitonic_desc(keys, CAP, 1024, threadIdx.x);
  for (int k = threadIdx.x; k < TOPK; k += 1024) {
    u64 key = keys[k];
    s1s[ch * TOPK + k] = __uint_as_float((u32)(key >> 32));
    s1i[ch * TOPK + k] = (int)(~(u32)key);
  }
}

// Per-batch top-100 over the 10*100 stage-1 candidates; write final outputs.
__global__ __launch_bounds__(256) void batch_topk_kernel(
    const float* __restrict__ s1s, const int* __restrict__ s1i,
    float* __restrict__ out) {
  const int b = blockIdx.x;  // 8 batches
  __shared__ u64 keys[1024];
  for (int i = threadIdx.x; i < 1024; i += 256) {
    u64 k = 0;
    if (i < 1000) {
      u32 vb = __float_as_uint(s1s[b * 1000 + i]);
      k = ((u64)vb << 32) | (u32)(~(u32)i);
    }
    keys[i] = k;
  }
  bitonic_desc(keys, 1024, 256, threadIdx.x);
  for (int k = threadIdx.x; k < TOPK; k += 256) {
    u64 key = keys[k];
    float sc = __uint_as_float((u32)(key >> 32));
    int flat = (int)(~(u32)key);          // c*100 + j
    int cls = flat / 100;
    int spatial = s1i[b * 1000 + flat];   // index within h*w
    out[0 * 800 + b * TOPK + k] = sc;
    out[1 * 800 + b * TOPK + k] = (float)spatial;
    out[2 * 800 + b * TOPK + k] = (float)cls;
    out[3 * 800 + b * TOPK + k] = (float)(spatial >> 9);   // y = idx / 512
    out[4 * 800 + b * TOPK + k] = (float)(spatial & 511);  // x = idx % 512
  }
}

extern "C" void kernel_launch(void* const* d_in, const int* in_sizes, int n_in,
                              void* d_out, int out_size, void* d_ws, size_t ws_size,
                              hipStream_t stream) {
  const float* heat = (const float*)d_in[0];
  char* ws = (char*)d_ws;
  u32*   hist   = (u32*)  (ws + OFF_HIST);
  int*   cnt    = (int*)  (ws + OFF_CNT);
  int*   thresh = (int*)  (ws + OFF_THRESH);
  float* cv     = (float*)(ws + OFF_CV);
  int*   ci     = (int*)  (ws + OFF_CI);
  float* s1s    = (float*)(ws + OFF_S1S);
  int*   s1i    = (int*)  (ws + OFF_S1I);
  float* out = (float*)d_out;

  hipMemsetAsync(d_ws, 0, ZERO_BYTES, stream);

  dim3 nms_grid(128, CHANNELS);  // 128 blocks * 2048 px = 512*512 per channel
  nms_kernel<false><<<nms_grid, 256, 0, stream>>>(heat, hist, thresh, cv, ci, cnt);
  thresh_kernel<<<CHANNELS, 256, 0, stream>>>(hist, thresh);
  nms_kernel<true><<<nms_grid, 256, 0, stream>>>(heat, hist, thresh, cv, ci, cnt);
  select_kernel<<<CHANNELS, 1024, 0, stream>>>(cv, ci, cnt, s1s, s1i);
  batch_topk_kernel<<<8, 256, 0, stream>>>(s1s, s1i, out);
}